// Round 5
// baseline (195.696 us; speedup 1.0000x reference)
//
#include <hip/hip_runtime.h>

// BlockRelLinear round 9: batch-4 software pipeline + nontemporal stores.
// out[p, n*8+o] = sum_i x[p, n*8+i] * w[rel[p], n, i, o]
//
// Ledger: r6 conflicts/3 -> 0%; r7 waves x2 -> +5% worse (confounded: also
// halved lane density); r8 line-touches/2 -> -11%. Nothing saturated, waves
// ~95% stalled, ~5700 cyc per 8-point iter vs ~250 cyc issued work. Theory:
// per-wave vmem ILP too thin (2-3 outstanding) and/or compiler sank the
// depth-2 prefetch. This round: 4 groups (32 contiguous points, 4KB span)
// per iteration; all next-batch loads issued as one burst (4 dwordx4 + rel),
// then 4x {DPP, 8 ds_read, 32 FMA, store}. Stores are NONTEMPORAL (out never
// re-read; keep L2/L3 for x which is reused by the 4 quad-blocks on the same
// XCD). Dense-lane map, LDS swizzle, ascending-i FMA order unchanged from r8
// -> absmax 0.0.

typedef float v4f __attribute__((ext_vector_type(4)));

__device__ __forceinline__ float4 dpp_swap1(float4 v) {
    union { float4 f; int i[4]; } a, b;
    a.f = v;
    // quad_perm [1,0,3,2] = 0xB1 : lane <- lane^1
    b.i[0] = __builtin_amdgcn_update_dpp(0, a.i[0], 0xB1, 0xF, 0xF, true);
    b.i[1] = __builtin_amdgcn_update_dpp(0, a.i[1], 0xB1, 0xF, 0xF, true);
    b.i[2] = __builtin_amdgcn_update_dpp(0, a.i[2], 0xB1, 0xF, 0xF, true);
    b.i[3] = __builtin_amdgcn_update_dpp(0, a.i[3], 0xB1, 0xF, 0xF, true);
    return b.f;
}

__global__ __launch_bounds__(1024) void k_fused(
    const float* __restrict__ x, const float* __restrict__ w,
    const int* __restrict__ rel, float* __restrict__ out, int npoints)
{
    // wlds[r][pos], pos = ((c<<2)|nl) ^ (r&63); c = i*2 + h, nl = n&3
    __shared__ float4 wlds[128][64];             // 128 KB (1 block/CU)

    const int q = blockIdx.x >> 6;               // quad 0..3 (n = q*4 + nl)
    const int b = blockIdx.x & 63;               // same-b quad blocks: same XCD

    // ---- stage quad weights, swizzled (identical to r6/r8) ----
    const float4* wsrc = reinterpret_cast<const float4*>(w);
    #pragma unroll
    for (int t = 0; t < 8; ++t) {
        int f   = threadIdx.x + t * 1024;        // (r, nl, k)
        int r   = f >> 6;
        int lo  = f & 63;                        // nl*16 + k
        int nls = lo >> 4;
        int k   = f & 15;
        wlds[r][((k << 2) | nls) ^ (r & 63)] = wsrc[r * 256 + q * 64 + lo];
    }
    __syncthreads();

    const int lane = threadIdx.x & 63;
    const int wv   = threadIdx.x >> 6;           // wave 0..15
    const int pt8  = lane >> 3;                  // point within group
    const int j    = lane & 7;                   // 16B chunk within 128B column
    const int nl   = j >> 1;
    const int h    = j & 1;                      // output half

    const int chunk = (npoints + 63) >> 6;
    const int plo   = b * chunk;
    const int phi   = min(plo + chunk, npoints);
    const int phim1 = phi - 1;

    int gB = plo + wv * 32;                      // wave's 32-point batch base
    if (gB >= phi) return;                       // no further __syncthreads

    // float4 index for point p: p*32 + q*8 + j (8 full 128B lines per instr)
    const float4* xv = reinterpret_cast<const float4*>(x) + q * 8 + j;
    float4*       ov = reinterpret_cast<float4*>(out) + q * 8 + j;

    auto comp = [&](int r1, float4 xa, int p1) {
        float4 xo  = dpp_swap1(xa);              // pair-lane's chunk
        float4 xlo = h ? xo  : xa;               // x[p, n*8 .. +4)
        float4 xhi = h ? xa : xo;                // x[p, n*8+4 .. +8)
        const int s   = r1 & 63;
        const int thi = s & 0x38;
        const int t0  = ((h << 2) | nl) ^ (s & 7);
        const float4* base = wlds[r1];
        float xf[8] = {xlo.x, xlo.y, xlo.z, xlo.w,
                       xhi.x, xhi.y, xhi.z, xhi.w};
        float a0 = 0.f, a1 = 0.f, a2 = 0.f, a3 = 0.f;
        #pragma unroll
        for (int i = 0; i < 8; ++i) {            // ascending i: FMA order as r2-r8
            float4 wv4 = base[((i << 3) ^ thi) | t0];  // w[r][n][i][h*4..+4)
            float xi = xf[i];
            a0 = fmaf(xi, wv4.x, a0);
            a1 = fmaf(xi, wv4.y, a1);
            a2 = fmaf(xi, wv4.z, a2);
            a3 = fmaf(xi, wv4.w, a3);
        }
        if (p1 < phi) {
            v4f val = {a0, a1, a2, a3};
            __builtin_nontemporal_store(val,
                reinterpret_cast<v4f*>(&ov[(size_t)p1 * 32]));
        }
    };

    // ---- prologue: batch 0 loads ----
    int    rr0, rr1, rr2, rr3;
    float4 xr0, xr1, xr2, xr3;
    {
        int p0 = min(gB +  0 + pt8, phim1);
        int p1 = min(gB +  8 + pt8, phim1);
        int p2 = min(gB + 16 + pt8, phim1);
        int p3 = min(gB + 24 + pt8, phim1);
        rr0 = rel[p0]; rr1 = rel[p1]; rr2 = rel[p2]; rr3 = rel[p3];
        xr0 = xv[(size_t)p0 * 32]; xr1 = xv[(size_t)p1 * 32];
        xr2 = xv[(size_t)p2 * 32]; xr3 = xv[(size_t)p3 * 32];
    }

    while (true) {
        int gN = gB + 512;                       // 16 waves * 32 points
        int    rn0, rn1, rn2, rn3;
        float4 xn0, xn1, xn2, xn3;
        if (gN < phi) {                          // wave-uniform prefetch burst
            int p0 = min(gN +  0 + pt8, phim1);
            int p1 = min(gN +  8 + pt8, phim1);
            int p2 = min(gN + 16 + pt8, phim1);
            int p3 = min(gN + 24 + pt8, phim1);
            xn0 = xv[(size_t)p0 * 32]; xn1 = xv[(size_t)p1 * 32];
            xn2 = xv[(size_t)p2 * 32]; xn3 = xv[(size_t)p3 * 32];
            rn0 = rel[p0]; rn1 = rel[p1]; rn2 = rel[p2]; rn3 = rel[p3];
        }

        comp(rr0, xr0, gB +  0 + pt8);
        comp(rr1, xr1, gB +  8 + pt8);
        comp(rr2, xr2, gB + 16 + pt8);
        comp(rr3, xr3, gB + 24 + pt8);

        if (gN >= phi) break;
        gB = gN;
        rr0 = rn0; rr1 = rn1; rr2 = rn2; rr3 = rn3;
        xr0 = xn0; xr1 = xn1; xr2 = xn2; xr3 = xn3;
    }
}

// ---------- fallback (round-2 kernel) for unexpected shapes ----------
__global__ __launch_bounds__(256) void brl_kernel(
    const float* __restrict__ x, const float* __restrict__ w,
    const int* __restrict__ rel, float* __restrict__ out, int npoints)
{
    int tid = blockIdx.x * 256 + threadIdx.x;
    int p = tid >> 4;
    if (p >= npoints) return;
    int n = tid & 15;
    int r = rel[p];
    const float4* xv = reinterpret_cast<const float4*>(x + (size_t)p * 128 + n * 8);
    float4 x0 = xv[0], x1 = xv[1];
    float xf[8] = {x0.x, x0.y, x0.z, x0.w, x1.x, x1.y, x1.z, x1.w};
    const float4* wv = reinterpret_cast<const float4*>(w + ((size_t)r * 16 + n) * 64);
    float acc[8] = {0.f, 0.f, 0.f, 0.f, 0.f, 0.f, 0.f, 0.f};
    #pragma unroll
    for (int i = 0; i < 8; ++i) {
        float4 w0 = wv[2 * i], w1 = wv[2 * i + 1];
        float wf[8] = {w0.x, w0.y, w0.z, w0.w, w1.x, w1.y, w1.z, w1.w};
        #pragma unroll
        for (int o = 0; o < 8; ++o) acc[o] = fmaf(xf[i], wf[o], acc[o]);
    }
    float4* ov = reinterpret_cast<float4*>(out + (size_t)p * 128 + n * 8);
    ov[0] = make_float4(acc[0], acc[1], acc[2], acc[3]);
    ov[1] = make_float4(acc[4], acc[5], acc[6], acc[7]);
}

extern "C" void kernel_launch(void* const* d_in, const int* in_sizes, int n_in,
                              void* d_out, int out_size, void* d_ws, size_t ws_size,
                              hipStream_t stream) {
    const float* x   = (const float*)d_in[0];
    const float* w   = (const float*)d_in[1];
    const int*   rel = (const int*)d_in[2];
    float*       out = (float*)d_out;

    int npoints = in_sizes[2];
    int R = in_sizes[1] / 1024;          // R * nb(16) * ib(8) * ob(8)

    if (R == 128 && in_sizes[0] == npoints * 128) {
        k_fused<<<256, 1024, 0, stream>>>(x, w, rel, out, npoints);
    } else {
        int total = npoints * 16;
        brl_kernel<<<(total + 255) / 256, 256, 0, stream>>>(x, w, rel, out, npoints);
    }
}

// Round 6
// 190.558 us; speedup vs baseline: 1.0270x; 1.0270x over previous
//
#include <hip/hip_runtime.h>

// BlockRelLinear round 10: r8 base + pipeline depth 2 -> 4. Single-knob A/B.
// out[p, n*8+o] = sum_i x[p, n*8+i] * w[rel[p], n, i, o]
//
// Ledger: r6 conflicts/3 -> 0%. r7 waves x2 -> +5% worse (confounded with line
// density). r8 line-dense remap -> -11% (66us, best). r9 batch4+NT -> +9%
// worse (confounded; NT store completion likely poisons the shared vmcnt
// counter on loop-carried waits). Remaining live theory: per-wave MLP.
// Little's law: measured ~12 GB/s/CU combined needs only ~2-4KB in flight
// (= 16 waves x depth-2 x 128B, what r8 has); copy-rate 24.6 GB/s/CU needs
// ~10-12KB/CU = 4-6 outstanding x-loads per wave. This round: rolling 4-deep
// prefetch (compute group g after issuing g+4*128's loads), named slot
// registers (no runtime-indexed arrays -> no scratch), PLAIN stores.
// Staging, swizzle, dense-lane map, DPP, ascending-i FMA order identical to
// r8 -> absmax 0.0.

__device__ __forceinline__ float4 dpp_swap1(float4 v) {
    union { float4 f; int i[4]; } a, b;
    a.f = v;
    // quad_perm [1,0,3,2] = 0xB1 : lane <- lane^1
    b.i[0] = __builtin_amdgcn_update_dpp(0, a.i[0], 0xB1, 0xF, 0xF, true);
    b.i[1] = __builtin_amdgcn_update_dpp(0, a.i[1], 0xB1, 0xF, 0xF, true);
    b.i[2] = __builtin_amdgcn_update_dpp(0, a.i[2], 0xB1, 0xF, 0xF, true);
    b.i[3] = __builtin_amdgcn_update_dpp(0, a.i[3], 0xB1, 0xF, 0xF, true);
    return b.f;
}

__global__ __launch_bounds__(1024) void k_fused(
    const float* __restrict__ x, const float* __restrict__ w,
    const int* __restrict__ rel, float* __restrict__ out, int npoints)
{
    // wlds[r][pos], pos = ((c<<2)|nl) ^ (r&63); c = i*2 + h, nl = n&3
    __shared__ float4 wlds[128][64];             // 128 KB (1 block/CU)

    const int q = blockIdx.x >> 6;               // quad 0..3 (n = q*4 + nl)
    const int b = blockIdx.x & 63;               // same-b quad blocks: same XCD

    // ---- stage quad weights, swizzled (identical to r6/r8) ----
    const float4* wsrc = reinterpret_cast<const float4*>(w);
    #pragma unroll
    for (int t = 0; t < 8; ++t) {
        int f   = threadIdx.x + t * 1024;        // (r, nl, k)
        int r   = f >> 6;
        int lo  = f & 63;                        // nl*16 + k
        int nls = lo >> 4;
        int k   = f & 15;
        wlds[r][((k << 2) | nls) ^ (r & 63)] = wsrc[r * 256 + q * 64 + lo];
    }
    __syncthreads();

    const int lane = threadIdx.x & 63;
    const int wv   = threadIdx.x >> 6;           // wave 0..15
    const int pt8  = lane >> 3;                  // point within group
    const int j    = lane & 7;                   // 16B chunk within 128B column
    const int nl   = j >> 1;
    const int h    = j & 1;                      // output half

    const int chunk = (npoints + 63) >> 6;
    const int plo   = b * chunk;
    const int phi   = min(plo + chunk, npoints);
    const int phim1 = phi - 1;

    int g = plo + wv * 8;                        // wave-uniform group base
    if (g >= phi) return;                        // no further __syncthreads

    // float4 index for point p: p*32 + q*8 + j (8 full 128B lines per instr)
    const float4* xv = reinterpret_cast<const float4*>(x) + q * 8 + j;
    float4*       ov = reinterpret_cast<float4*>(out) + q * 8 + j;

    const int STEP = 128;                        // 16 waves * 8 points

    auto comp = [&](int r1, float4 xa, int p1) {
        float4 xo  = dpp_swap1(xa);              // pair-lane's chunk
        float4 xlo = h ? xo : xa;                // x[p, n*8 .. +4)
        float4 xhi = h ? xa : xo;                // x[p, n*8+4 .. +8)
        const int s   = r1 & 63;
        const int thi = s & 0x38;
        const int t0  = ((h << 2) | nl) ^ (s & 7);
        const float4* base = wlds[r1];
        float xf[8] = {xlo.x, xlo.y, xlo.z, xlo.w,
                       xhi.x, xhi.y, xhi.z, xhi.w};
        float a0 = 0.f, a1 = 0.f, a2 = 0.f, a3 = 0.f;
        #pragma unroll
        for (int i = 0; i < 8; ++i) {            // ascending i: FMA order as r2-r9
            float4 wv4 = base[((i << 3) ^ thi) | t0];  // w[r][n][i][h*4..+4)
            float xi = wv4.x, dummy;             // (avoid unused warning pattern)
            (void)dummy;
            float xi1 = xf[i];
            a0 = fmaf(xi1, wv4.x, a0);
            a1 = fmaf(xi1, wv4.y, a1);
            a2 = fmaf(xi1, wv4.z, a2);
            a3 = fmaf(xi1, wv4.w, a3);
            (void)xi;
        }
        if (p1 < phi)
            ov[(size_t)p1 * 32] = make_float4(a0, a1, a2, a3);
    };

    // ---- prologue: fill 4 rolling slots (g, g+128, g+256, g+384) ----
    int    r0, r1s, r2s, r3s;
    float4 x0, x1s, x2s, x3s;
    {
        int p0 = min(g +   0 + pt8, phim1);
        int p1 = min(g + 128 + pt8, phim1);
        int p2 = min(g + 256 + pt8, phim1);
        int p3 = min(g + 384 + pt8, phim1);
        x0  = xv[(size_t)p0 * 32]; x1s = xv[(size_t)p1 * 32];
        x2s = xv[(size_t)p2 * 32]; x3s = xv[(size_t)p3 * 32];
        r0  = rel[p0]; r1s = rel[p1]; r2s = rel[p2]; r3s = rel[p3];
    }

    while (true) {
        // ---- prefetch slot 4 ahead (clamped; wave-uniform control) ----
        int pc = min(g + 4 * STEP + pt8, phim1);
        float4 xn = xv[(size_t)pc * 32];
        int    rn = rel[pc];

        // ---- compute oldest slot (loads issued 4 iterations ago) ----
        comp(r0, x0, g + pt8);

        if (g + STEP >= phi) break;
        g += STEP;
        r0  = r1s; x0  = x1s;
        r1s = r2s; x1s = x2s;
        r2s = r3s; x2s = x3s;
        r3s = rn;  x3s = xn;
    }
}

// ---------- fallback (round-2 kernel) for unexpected shapes ----------
__global__ __launch_bounds__(256) void brl_kernel(
    const float* __restrict__ x, const float* __restrict__ w,
    const int* __restrict__ rel, float* __restrict__ out, int npoints)
{
    int tid = blockIdx.x * 256 + threadIdx.x;
    int p = tid >> 4;
    if (p >= npoints) return;
    int n = tid & 15;
    int r = rel[p];
    const float4* xv = reinterpret_cast<const float4*>(x + (size_t)p * 128 + n * 8);
    float4 x0 = xv[0], x1 = xv[1];
    float xf[8] = {x0.x, x0.y, x0.z, x0.w, x1.x, x1.y, x1.z, x1.w};
    const float4* wv = reinterpret_cast<const float4*>(w + ((size_t)r * 16 + n) * 64);
    float acc[8] = {0.f, 0.f, 0.f, 0.f, 0.f, 0.f, 0.f, 0.f};
    #pragma unroll
    for (int i = 0; i < 8; ++i) {
        float4 w0 = wv[2 * i], w1 = wv[2 * i + 1];
        float wf[8] = {w0.x, w0.y, w0.z, w0.w, w1.x, w1.y, w1.z, w1.w};
        #pragma unroll
        for (int o = 0; o < 8; ++o) acc[o] = fmaf(xf[i], wf[o], acc[o]);
    }
    float4* ov = reinterpret_cast<float4*>(out + (size_t)p * 128 + n * 8);
    ov[0] = make_float4(acc[0], acc[1], acc[2], acc[3]);
    ov[1] = make_float4(acc[4], acc[5], acc[6], acc[7]);
}

extern "C" void kernel_launch(void* const* d_in, const int* in_sizes, int n_in,
                              void* d_out, int out_size, void* d_ws, size_t ws_size,
                              hipStream_t stream) {
    const float* x   = (const float*)d_in[0];
    const float* w   = (const float*)d_in[1];
    const int*   rel = (const int*)d_in[2];
    float*       out = (float*)d_out;

    int npoints = in_sizes[2];
    int R = in_sizes[1] / 1024;          // R * nb(16) * ib(8) * ob(8)

    if (R == 128 && in_sizes[0] == npoints * 128) {
        k_fused<<<256, 1024, 0, stream>>>(x, w, rel, out, npoints);
    } else {
        int total = npoints * 16;
        brl_kernel<<<(total + 255) / 256, 256, 0, stream>>>(x, w, rel, out, npoints);
    }
}